// Round 1
// baseline (276.713 us; speedup 1.0000x reference)
//
#include <hip/hip_runtime.h>
#include <hip/hip_bf16.h>
#include <stdint.h>

typedef float  f32x4  __attribute__((ext_vector_type(4)));
typedef __bf16 bf16x8 __attribute__((ext_vector_type(8)));
typedef __bf16 bf16x4 __attribute__((ext_vector_type(4)));

static constexpr int NB = 8, NS = 1024, NE = 1024, NH = 16;

#define MFMA16(a, b, c) __builtin_amdgcn_mfma_f32_16x16x32_bf16((a), (b), (c), 0, 0, 0)

__device__ __forceinline__ void gload_lds16(const void* g, void* l) {
    __builtin_amdgcn_global_load_lds(
        (const __attribute__((address_space(1))) void*)g,
        (__attribute__((address_space(3))) void*)l, 16, 0, 0);
}

// ---------------------------------------------------------------------------
// Kernel 1: proj = cos(x + theta), written in two layouts:
//   proj [B,H,S,64]  (row-major over d)   -> Q and K fragments
//   projT[B,H,64,S]  (row-major over s)   -> V^T fragments (MFMA A operand)
// One block = one (b,h) pair x 64-row s-chunk. 256 threads.
// ---------------------------------------------------------------------------
__global__ __launch_bounds__(256) void k_proj(const float* __restrict__ x,
                                              const float* __restrict__ theta,
                                              __bf16* __restrict__ proj,
                                              __bf16* __restrict__ projT) {
    __shared__ float sm[64][65];  // [d][s] f32, +1 pad
    const int bid  = blockIdx.x;        // 0..2047
    const int bh   = bid >> 4;          // b*16 + h
    const int st0  = (bid & 15) << 6;   // s-chunk base
    const int b    = bh >> 4, h = bh & 15;
    const int t    = threadIdx.x;
    const int srow = t >> 2;            // 0..63
    const int j4   = t & 3;

    const float* xrow = x + ((size_t)(b * NS + st0 + srow)) * NE + h * 64;
    __bf16* prow = proj + ((size_t)bh * NS + st0 + srow) * 64;

#pragma unroll
    for (int k = 0; k < 4; ++k) {
        const int d = k * 16 + j4 * 4;
        float4 xv = *(const float4*)(xrow + d);
        float4 tv = *(const float4*)(theta + d);
        float c0 = __cosf(xv.x + tv.x);
        float c1 = __cosf(xv.y + tv.y);
        float c2 = __cosf(xv.z + tv.z);
        float c3 = __cosf(xv.w + tv.w);
        bf16x4 pv = {(__bf16)c0, (__bf16)c1, (__bf16)c2, (__bf16)c3};
        *(bf16x4*)(prow + d) = pv;
        sm[d + 0][srow] = c0;
        sm[d + 1][srow] = c1;
        sm[d + 2][srow] = c2;
        sm[d + 3][srow] = c3;
    }
    __syncthreads();

    const int drow = t >> 2;  // 0..63 (d index)
    bf16x8 o0, o1;
#pragma unroll
    for (int i = 0; i < 8; ++i) {
        o0[i] = (__bf16)sm[drow][j4 * 16 + i];
        o1[i] = (__bf16)sm[drow][j4 * 16 + 8 + i];
    }
    __bf16* dst = projT + ((size_t)bh * 64 + drow) * NS + st0 + j4 * 16;
    *(bf16x8*)dst = o0;
    *(bf16x8*)(dst + 8) = o1;
}

// ---------------------------------------------------------------------------
// Kernel 2: W (f32 [E,E]) -> bf16
// ---------------------------------------------------------------------------
__global__ __launch_bounds__(256) void k_cvtW(const float* __restrict__ W,
                                              __bf16* __restrict__ Wb) {
    const int i = (blockIdx.x * 256 + threadIdx.x) * 4;
    float4 v = *(const float4*)(W + i);
    bf16x4 o = {(__bf16)v.x, (__bf16)v.y, (__bf16)v.z, (__bf16)v.w};
    *(bf16x4*)(Wb + i) = o;
}

// ---------------------------------------------------------------------------
// Kernel 3: flash attention, Q=K=V=proj. Swapped-operand scores:
//   S^T = mfma(A=K, B=Q)  -> lane holds S^T[k=4g+r (+16*tile), q=c]
//   softmax state (m, lsum) is per-lane scalar (q = c, replicated over g)
//   P redistributed to B-fragment layout via 16 __shfl, then
//   out^T = mfma(A=V^T, B=P^T) accumulated over kv tiles of 32.
// Block = 256 threads = 4 waves; wave w handles 16 q-rows; block covers
// one (b,h) x 64 q-rows. Grid = 128 * 16 = 2048.
// ---------------------------------------------------------------------------
__global__ __launch_bounds__(256) void k_attn(const __bf16* __restrict__ proj,
                                              const __bf16* __restrict__ projT,
                                              __bf16* __restrict__ attn_out) {
    __shared__ float ep[4][16][69];  // epilogue transpose, per wave

    const int bid  = blockIdx.x;   // 0..2047
    const int bh   = bid >> 4;
    const int qt   = bid & 15;
    const int t    = threadIdx.x;
    const int w    = t >> 6;
    const int lane = t & 63;
    const int g    = lane >> 4;    // 0..3
    const int c    = lane & 15;    // 0..15
    const int qbase = qt * 64 + w * 16;

    const __bf16* P  = proj  + (size_t)bh * NS * 64;
    const __bf16* PT = projT + (size_t)bh * 64 * NS;

    // Q fragments (B operand: lane holds Q[q=c][d = 32*half + 8g + i])
    bf16x8 bq0 = *(const bf16x8*)(P + (size_t)(qbase + c) * 64 + g * 8);
    bf16x8 bq1 = *(const bf16x8*)(P + (size_t)(qbase + c) * 64 + 32 + g * 8);

    f32x4 acc[4];
#pragma unroll
    for (int dc = 0; dc < 4; ++dc) acc[dc] = (f32x4){0.f, 0.f, 0.f, 0.f};
    float m2 = -1e30f, lsum = 0.f;
    const float csc = 0.18033688f;  // (1/sqrt(64)) * log2(e)

    const int s0l = (((2 * g) & 3) << 4) | c;
    const int s1l = (((2 * g + 1) & 3) << 4) | c;

    for (int kv = 0; kv < NS; kv += 32) {
        const __bf16* Kp = P + (size_t)kv * 64;
        // K fragments (A operand: lane holds K[krow = 16*tile + c][d = 32*half + 8g + i])
        bf16x8 ak00 = *(const bf16x8*)(Kp + (size_t)c * 64 + g * 8);
        bf16x8 ak01 = *(const bf16x8*)(Kp + (size_t)c * 64 + 32 + g * 8);
        bf16x8 ak10 = *(const bf16x8*)(Kp + (size_t)(16 + c) * 64 + g * 8);
        bf16x8 ak11 = *(const bf16x8*)(Kp + (size_t)(16 + c) * 64 + 32 + g * 8);

        f32x4 st0 = (f32x4){0.f, 0.f, 0.f, 0.f};
        f32x4 st1 = (f32x4){0.f, 0.f, 0.f, 0.f};
        st0 = MFMA16(ak00, bq0, st0);
        st0 = MFMA16(ak01, bq1, st0);
        st1 = MFMA16(ak10, bq0, st1);
        st1 = MFMA16(ak11, bq1, st1);

        // scaled to exp2 domain
        float p0[4], p1[4];
        float tm = -1e30f;
#pragma unroll
        for (int r = 0; r < 4; ++r) {
            p0[r] = st0[r] * csc;
            p1[r] = st1[r] * csc;
            tm = fmaxf(tm, fmaxf(p0[r], p1[r]));
        }
        tm = fmaxf(tm, __shfl_xor(tm, 16));
        tm = fmaxf(tm, __shfl_xor(tm, 32));
        const float mnew = fmaxf(m2, tm);
        const float f = exp2f(m2 - mnew);
        m2 = mnew;

        float rs = 0.f;
#pragma unroll
        for (int r = 0; r < 4; ++r) {
            p0[r] = exp2f(p0[r] - mnew);
            p1[r] = exp2f(p1[r] - mnew);
            rs += p0[r] + p1[r];
        }
        rs += __shfl_xor(rs, 16);
        rs += __shfl_xor(rs, 32);
        lsum = lsum * f + rs;
#pragma unroll
        for (int dc = 0; dc < 4; ++dc) {
            acc[dc][0] *= f; acc[dc][1] *= f; acc[dc][2] *= f; acc[dc][3] *= f;
        }

        // Redistribute P^T (D layout) -> B-fragment layout: pb[i] = P^T[8g+i, c]
        bf16x8 pbv;
#pragma unroll
        for (int r = 0; r < 4; ++r) {
            float a0 = __shfl(p0[r], s0l);
            float a1 = __shfl(p1[r], s0l);
            float b0 = __shfl(p0[r], s1l);
            float b1 = __shfl(p1[r], s1l);
            pbv[r]     = (__bf16)((g < 2) ? a0 : a1);
            pbv[4 + r] = (__bf16)((g < 2) ? b0 : b1);
        }

        // PV: out^T[d, q] += V^T[d, k] * P^T[k, q]
#pragma unroll
        for (int dc = 0; dc < 4; ++dc) {
            bf16x8 av = *(const bf16x8*)(PT + (size_t)(dc * 16 + c) * NS + kv + g * 8);
            acc[dc] = MFMA16(av, pbv, acc[dc]);
        }
    }

    // Epilogue: divide by lsum, LDS transpose, coalesced bf16 store.
    const float inv = 1.0f / lsum;
#pragma unroll
    for (int dc = 0; dc < 4; ++dc) {
#pragma unroll
        for (int r = 0; r < 4; ++r)
            ep[w][c][dc * 16 + 4 * g + r] = acc[dc][r] * inv;
    }
    __syncthreads();

    const int orow = lane >> 2;  // q-row within wave tile
    const int och  = lane & 3;   // 16-wide d-chunk
    bf16x8 o0, o1;
#pragma unroll
    for (int i = 0; i < 8; ++i) {
        o0[i] = (__bf16)ep[w][orow][och * 16 + i];
        o1[i] = (__bf16)ep[w][orow][och * 16 + 8 + i];
    }
    __bf16* dst = attn_out +
        ((size_t)(bh >> 4) * NS + qt * 64 + w * 16 + orow) * NE + (bh & 15) * 64 + och * 16;
    *(bf16x8*)dst = o0;
    *(bf16x8*)(dst + 8) = o1;
}

// ---------------------------------------------------------------------------
// Kernel 4: C[M,N] = A[M,K](bf16) x W^T  (y[i,j] = sum_k A[i,k]*Wb[j,k])
// m97 structure: 128x128 tile, BK=32, global_load_lds(16B), 4 waves, 4x4 frags.
// M=8192, N=1024, K=1024.
// ---------------------------------------------------------------------------
__global__ __launch_bounds__(256) void k_gemm(const __bf16* __restrict__ A,
                                              const __bf16* __restrict__ Bw,
                                              float* __restrict__ C) {
    constexpr int K = 1024, N = 1024;
    __shared__ __bf16 As[128 * 32];
    __shared__ __bf16 Bs[128 * 32];

    const int t = threadIdx.x;
    const int lane = t & 63, w = t >> 6;
    const int g = lane >> 4, c = lane & 15;
    const int wr = w >> 1, wc = w & 1;
    const size_t row0 = (size_t)blockIdx.x * 128;
    const size_t col0 = (size_t)blockIdx.y * 128;

    const char* Ag = (const char*)(A + row0 * K);
    const char* Bg = (const char*)(Bw + col0 * K);
    char* AsB = (char*)As;
    char* BsB = (char*)Bs;
    const int srow  = t >> 2;          // 0..63 (staging row)
    const int sbyte = (t & 3) * 16;    // byte offset within 64B row

    f32x4 acc[4][4];
#pragma unroll
    for (int m = 0; m < 4; ++m)
#pragma unroll
        for (int n = 0; n < 4; ++n) acc[m][n] = (f32x4){0.f, 0.f, 0.f, 0.f};

    for (int kb = 0; kb < K; kb += 32) {
        gload_lds16(Ag + (size_t)srow * (K * 2) + kb * 2 + sbyte, AsB + t * 16);
        gload_lds16(Ag + (size_t)(srow + 64) * (K * 2) + kb * 2 + sbyte, AsB + 4096 + t * 16);
        gload_lds16(Bg + (size_t)srow * (K * 2) + kb * 2 + sbyte, BsB + t * 16);
        gload_lds16(Bg + (size_t)(srow + 64) * (K * 2) + kb * 2 + sbyte, BsB + 4096 + t * 16);
        __syncthreads();

        bf16x8 a[4], b[4];
#pragma unroll
        for (int m = 0; m < 4; ++m)
            a[m] = *(const bf16x8*)(As + (wr * 64 + m * 16 + c) * 32 + g * 8);
#pragma unroll
        for (int n = 0; n < 4; ++n)
            b[n] = *(const bf16x8*)(Bs + (wc * 64 + n * 16 + c) * 32 + g * 8);
#pragma unroll
        for (int m = 0; m < 4; ++m)
#pragma unroll
            for (int n = 0; n < 4; ++n) acc[m][n] = MFMA16(a[m], b[n], acc[m][n]);
        __syncthreads();
    }

#pragma unroll
    for (int m = 0; m < 4; ++m)
#pragma unroll
        for (int n = 0; n < 4; ++n)
#pragma unroll
            for (int r = 0; r < 4; ++r)
                C[(row0 + wr * 64 + m * 16 + 4 * g + r) * N + col0 + wc * 64 + n * 16 + c] =
                    acc[m][n][r];
}

// ---------------------------------------------------------------------------
extern "C" void kernel_launch(void* const* d_in, const int* in_sizes, int n_in,
                              void* d_out, int out_size, void* d_ws, size_t ws_size,
                              hipStream_t stream) {
    const float* x     = (const float*)d_in[0];
    const float* theta = (const float*)d_in[1];
    const float* W     = (const float*)d_in[2];
    float* out = (float*)d_out;

    char* ws = (char*)d_ws;
    __bf16* proj  = (__bf16*)(ws);                 // 16 MiB  [B,H,S,64]
    __bf16* projT = (__bf16*)(ws + 16777216);      // 16 MiB  [B,H,64,S]
    __bf16* Wb    = (__bf16*)(ws + 33554432);      //  2 MiB  [E,E]
    __bf16* ao    = (__bf16*)(ws + 35651584);      // 16 MiB  [B,S,E]

    k_proj<<<NB * NH * (NS / 64), 256, 0, stream>>>(x, theta, proj, projT);
    k_cvtW<<<(NE * NE / 4) / 256, 256, 0, stream>>>(W, Wb);
    k_attn<<<NB * NH * (NS / 64), 256, 0, stream>>>(proj, projT, ao);
    dim3 gg(NB * NS / 128, NE / 128);
    k_gemm<<<gg, 256, 0, stream>>>(ao, Wb, out);
}